// Round 7
// baseline (354.900 us; speedup 1.0000x reference)
//
#include <hip/hip_runtime.h>
#include <hip/hip_bf16.h>

#define NQ      10
#define NLAYERS 4
#define D_IN    784
#define BLOCK   1024           // 16 waves = 16 batch states per block (occupancy experiment:
                               // R6 @ BLOCK=256 measured OccupancyPercent=21% ~ 1.7 blocks/CU;
                               // a 16-wave block forces 16 waves/CU resident per block)

// Amplitude index i (10 bits): i = lane(6 bits, i[9:4]) * 16 + r(4 bits, i[3:0]).
// Qubit q sits at bit P = 9-q.  P>=4 -> lane qubit (lane bit P-4), P<4 -> register qubit.
// Lane-qubit cross-lane moves: xor mask 1,2 -> DPP quad_perm (VALU pipe);
// masks 4..32 -> ds_swizzle via __shfl_xor (DS pipe).
// NOTE occupancy floor: min-waves/EU >= 4 (via launch_bounds or waves_per_eu) makes the
// RA force 64 VGPRs and spill the statevector to scratch (R3/R5: 760 MB HBM write traffic,
// +120 us). (2,8) lets it settle at ~76-92 VGPRs with zero spill. Do not raise the floor.

template<int LB>
__device__ __forceinline__ float lane_xor(float v) {
    if constexpr (LB == 1) {        // quad_perm [1,0,3,2]
        return __int_as_float(__builtin_amdgcn_update_dpp(
            0, __float_as_int(v), 0xB1, 0xF, 0xF, false));
    } else if constexpr (LB == 2) { // quad_perm [2,3,0,1]
        return __int_as_float(__builtin_amdgcn_update_dpp(
            0, __float_as_int(v), 0x4E, 0xF, 0xF, false));
    } else {
        return __shfl_xor(v, LB, 64);
    }
}

// ---- generic complex 2x2 gate (Rot) on bit position P ----
template<int P>
__device__ __forceinline__ void rot_gate(float (&ax)[16], float (&ay)[16], int lane,
                                         float4 gA, float4 gB) {
    if constexpr (P >= 4) {
        const int lb = 1 << (P - 4);
        const bool hi = (lane & lb) != 0;
        const float gdx = hi ? gB.z : gA.x, gdy = hi ? gB.w : gA.y;   // diagonal
        const float gox = hi ? gB.x : gA.z, goy = hi ? gB.y : gA.w;   // off-diagonal
#pragma unroll
        for (int r = 0; r < 16; r++) {
            float ox = lane_xor<lb>(ax[r]);
            float oy = lane_xor<lb>(ay[r]);
            float vx = ax[r], vy = ay[r];
            ax[r] = gdx * vx - gdy * vy + gox * ox - goy * oy;
            ay[r] = gdx * vy + gdy * vx + gox * oy + goy * ox;
        }
    } else {
        const int m = 1 << P;
#pragma unroll
        for (int r = 0; r < 16; r++) {
            if (!(r & m)) {
                const int r1 = r | m;
                float x0 = ax[r], y0 = ay[r], x1 = ax[r1], y1 = ay[r1];
                ax[r]  = gA.x * x0 - gA.y * y0 + gA.z * x1 - gA.w * y1;
                ay[r]  = gA.x * y0 + gA.y * x0 + gA.z * y1 + gA.w * x1;
                ax[r1] = gB.x * x0 - gB.y * y0 + gB.z * x1 - gB.w * y1;
                ay[r1] = gB.x * y0 + gB.y * x0 + gB.z * y1 + gB.w * x1;
            }
        }
    }
}

// ---- CNOT: control bit PC, target bit PT (only the non-chain cases remain) ----
template<int PC, int PT>
__device__ __forceinline__ void cnot_gate(float (&ax)[16], float (&ay)[16], int lane) {
    if constexpr (PC >= 4 && PT < 4) {                // lane control, register target
        const int mt = 1 << PT;
        const bool ctl = (lane & (1 << (PC - 4))) != 0;
#pragma unroll
        for (int r = 0; r < 16; r++) {
            if (!(r & mt)) {
                const int r1 = r | mt;
                float x0 = ax[r], y0 = ay[r], x1 = ax[r1], y1 = ay[r1];
                ax[r]  = ctl ? x1 : x0;  ay[r]  = ctl ? y1 : y0;
                ax[r1] = ctl ? x0 : x1;  ay[r1] = ctl ? y0 : y1;
            }
        }
    } else if constexpr (PC < 4 && PT >= 4) {         // register control, lane target
        const int mc = 1 << PC, mt = 1 << (PT - 4);
#pragma unroll
        for (int r = 0; r < 16; r++) {
            if (r & mc) {
                ax[r] = __shfl_xor(ax[r], mt, 64);
                ay[r] = __shfl_xor(ay[r], mt, 64);
            }
        }
    } else {                                          // register-register: free rename
        const int mc = 1 << PC, mt = 1 << PT;
#pragma unroll
        for (int r = 0; r < 16; r++) {
            if ((r & mc) && !(r & mt)) {
                const int r1 = r | mt;
                float t;
                t = ax[r]; ax[r] = ax[r1]; ax[r1] = t;
                t = ay[r]; ay[r] = ay[r1]; ay[r1] = t;
            }
        }
    }
}

__global__ __launch_bounds__(BLOCK)
__attribute__((amdgpu_waves_per_eu(2, 8)))
void qnet_kernel(
    const float* __restrict__ x,
    const float* __restrict__ Wp,
    const float* __restrict__ bp,
    const float* __restrict__ qw,
    const float* __restrict__ Wo,
    const float* __restrict__ bo,
    float* __restrict__ out, int B)
{
    __shared__ __align__(16) float gates[NLAYERS * NQ * 8];  // Rot matrices (batch-independent)

    const int tid   = threadIdx.x;
    const int lane  = tid & 63;
    const int state = blockIdx.x * (BLOCK / 64) + (tid >> 6);

    // ---- Rot gate table (block-shared; the only barrier in the kernel) ----
    if (tid < NLAYERS * NQ) {
        float phi = qw[tid * 3 + 0];
        float th  = qw[tid * 3 + 1];
        float om  = qw[tid * 3 + 2];
        float s, c;   sincosf(0.5f * th, &s, &c);
        float sap, cap; sincosf(0.5f * (phi + om), &sap, &cap);
        float sam, cam; sincosf(0.5f * (phi - om), &sam, &cam);
        float* g = &gates[tid * 8];
        g[0] =  cap * c;  g[1] = -sap * c;   // u00
        g[2] = -cam * s;  g[3] = -sam * s;   // u01
        g[4] =  cam * s;  g[5] = -sam * s;   // u10
        g[6] =  cap * c;  g[7] =  sap * c;   // u11
    }
    __syncthreads();
    if (state >= B) return;

    // ---- projection: h = tanh(x[state] @ Wp^T + bp), one wave per state ----
    float acc[NQ];
#pragma unroll
    for (int q = 0; q < NQ; q++) acc[q] = 0.f;
    const float* xrow = x + (size_t)state * D_IN;
    for (int d = lane; d < D_IN; d += 64) {
        float xv = xrow[d];
#pragma unroll
        for (int q = 0; q < NQ; q++) acc[q] += xv * Wp[q * D_IN + d];
    }
#pragma unroll
    for (int q = 0; q < NQ; q++) {
#pragma unroll
        for (int o = 1; o < 64; o <<= 1) acc[q] += __shfl_xor(acc[q], o, 64);
    }
    // lane q (q<10) owns qubit q's RY coefficients
    float myc = 1.f, mys = 0.f;
    if (lane < NQ) {
        float h = tanhf(acc[lane] + bp[lane]);
        sincosf(0.5f * h, &mys, &myc);
    }

    // ---- statevector |0..0> in registers (SoA) ----
    float ax[16], ay[16];
#pragma unroll
    for (int r = 0; r < 16; r++) { ax[r] = 0.f; ay[r] = 0.f; }
    if (lane == 0) ax[0] = 1.f;

    // Pull-index for the composite lane-CNOT chain: src_lane = Gray(lane)
    const int bidx = (lane ^ (lane >> 1)) << 2;

    // ---- layer 0: RY fused into Rot (U = Rot * RY, wave-uniform) ----
    {
        const float* gl = &gates[0];
        float c, s;
#define FROTQ(Q) \
        c = __shfl(myc, Q, 64); s = __shfl(mys, Q, 64); \
        { float4 gA = *(const float4*)(gl + Q * 8); \
          float4 gB = *(const float4*)(gl + Q * 8 + 4); \
          float4 uA, uB; \
          uA.x = gA.x * c + gA.z * s;  uA.y = gA.y * c + gA.w * s; \
          uA.z = gA.z * c - gA.x * s;  uA.w = gA.w * c - gA.y * s; \
          uB.x = gB.x * c + gB.z * s;  uB.y = gB.y * c + gB.w * s; \
          uB.z = gB.z * c - gB.x * s;  uB.w = gB.w * c - gB.y * s; \
          rot_gate<9 - Q>(ax, ay, lane, uA, uB); }
        FROTQ(0) FROTQ(1) FROTQ(2) FROTQ(3) FROTQ(4)
        FROTQ(5) FROTQ(6) FROTQ(7) FROTQ(8) FROTQ(9)
#undef FROTQ
        // CNOT ring: composite of (9,8)(8,7)(7,6)(6,5)(5,4) as one lane permutation
#pragma unroll
        for (int r = 0; r < 16; r++) {
            ax[r] = __int_as_float(__builtin_amdgcn_ds_bpermute(bidx, __float_as_int(ax[r])));
            ay[r] = __int_as_float(__builtin_amdgcn_ds_bpermute(bidx, __float_as_int(ay[r])));
        }
        cnot_gate<4, 3>(ax, ay, lane);
        cnot_gate<3, 2>(ax, ay, lane);
        cnot_gate<2, 1>(ax, ay, lane);
        cnot_gate<1, 0>(ax, ay, lane);
        cnot_gate<0, 9>(ax, ay, lane);
    }

    // ---- layers 1..3 ----
    for (int l = 1; l < NLAYERS; l++) {
        const float* gl = &gates[l * NQ * 8];
#define ROTQ(Q) { float4 gA = *(const float4*)(gl + Q * 8); \
                  float4 gB = *(const float4*)(gl + Q * 8 + 4); \
                  rot_gate<9 - Q>(ax, ay, lane, gA, gB); }
        ROTQ(0) ROTQ(1) ROTQ(2) ROTQ(3) ROTQ(4)
        ROTQ(5) ROTQ(6) ROTQ(7) ROTQ(8) ROTQ(9)
#undef ROTQ
#pragma unroll
        for (int r = 0; r < 16; r++) {
            ax[r] = __int_as_float(__builtin_amdgcn_ds_bpermute(bidx, __float_as_int(ax[r])));
            ay[r] = __int_as_float(__builtin_amdgcn_ds_bpermute(bidx, __float_as_int(ay[r])));
        }
        cnot_gate<4, 3>(ax, ay, lane);
        cnot_gate<3, 2>(ax, ay, lane);
        cnot_gate<2, 1>(ax, ay, lane);
        cnot_gate<1, 0>(ax, ay, lane);
        cnot_gate<0, 9>(ax, ay, lane);
    }

    // ---- measurement: Z expectation per qubit ----
    float S = 0.f, zr3 = 0.f, zr2 = 0.f, zr1 = 0.f, zr0 = 0.f;
#pragma unroll
    for (int r = 0; r < 16; r++) {
        float pr = ax[r] * ax[r] + ay[r] * ay[r];
        S += pr;
        zr3 += (r & 8) ? -pr : pr;
        zr2 += (r & 4) ? -pr : pr;
        zr1 += (r & 2) ? -pr : pr;
        zr0 += (r & 1) ? -pr : pr;
    }
    float zq[NQ];
    zq[6] = zr3; zq[7] = zr2; zq[8] = zr1; zq[9] = zr0;       // register qubits
#pragma unroll
    for (int q = 0; q < 6; q++)                                // lane qubits: lane bit 5-q
        zq[q] = ((lane >> (5 - q)) & 1) ? -S : S;
#pragma unroll
    for (int q = 0; q < NQ; q++) {
#pragma unroll
        for (int o = 1; o < 64; o <<= 1) zq[q] += __shfl_xor(zq[q], o, 64);
    }

    // ---- output projection: out[state] = zq @ Wo^T + bo ----
    if (lane < NQ) {
        float o = bo[lane];
#pragma unroll
        for (int q = 0; q < NQ; q++) o += zq[q] * Wo[lane * NQ + q];
        out[(size_t)state * NQ + lane] = o;
    }
}

extern "C" void kernel_launch(void* const* d_in, const int* in_sizes, int n_in,
                              void* d_out, int out_size, void* d_ws, size_t ws_size,
                              hipStream_t stream) {
    const float* x  = (const float*)d_in[0];
    const float* Wp = (const float*)d_in[1];
    const float* bp = (const float*)d_in[2];
    const float* qw = (const float*)d_in[3];
    const float* Wo = (const float*)d_in[4];
    const float* bo = (const float*)d_in[5];
    float* out = (float*)d_out;

    const int B = in_sizes[0] / D_IN;                    // 8192
    const int blocks = (B + (BLOCK / 64) - 1) / (BLOCK / 64);
    hipLaunchKernelGGL(qnet_kernel, dim3(blocks), dim3(BLOCK), 0, stream,
                       x, Wp, bp, qw, Wo, bo, out, B);
}

// Round 9
// 209.134 us; speedup vs baseline: 1.6970x; 1.6970x over previous
//
#include <hip/hip_runtime.h>
#include <hip/hip_bf16.h>

#define NQ      10
#define NLAYERS 4
#define D_IN    784
#define BLOCK   256            // 4 waves = 4 batch states per block.
// LOCKED: BLOCK=256 + waves_per_eu(2,8). Raising the occupancy floor to >=4 waves/EU
// (launch_bounds(.,4), waves_per_eu(4,8), or BLOCK=1024 which implies 4 waves/EU) makes
// the RA force 64 VGPRs and spill the 32-reg statevector to scratch: 760+ MB HBM write
// traffic, +120-190 us (R3/R5/R7). (2,8) settles at ~76-92 VGPR, zero spill.
// LOCKED: reductions use plain __shfl_xor only. R8's DPP-based reductions + Walsh
// butterfly + readlane extraction passed first validation but diverged nondeterministically
// across graph replays (post-timing absmax 0.79). DPP stays confined to rot_gate's
// full-exec lane_xor<1,2>, which has been stable since R4.

// Amplitude index i (10 bits): i = lane(6 bits, i[9:4]) * 16 + r(4 bits, i[3:0]).
// Qubit q sits at bit P = 9-q.  P>=4 -> lane qubit (lane bit P-4), P<4 -> register qubit.

template<int LB>
__device__ __forceinline__ float lane_xor(float v) {
    if constexpr (LB == 1) {        // quad_perm [1,0,3,2]
        return __int_as_float(__builtin_amdgcn_update_dpp(
            0, __float_as_int(v), 0xB1, 0xF, 0xF, false));
    } else if constexpr (LB == 2) { // quad_perm [2,3,0,1]
        return __int_as_float(__builtin_amdgcn_update_dpp(
            0, __float_as_int(v), 0x4E, 0xF, 0xF, false));
    } else {
        return __shfl_xor(v, LB, 64);
    }
}

// ---- generic complex 2x2 gate (Rot) on bit position P ----
template<int P>
__device__ __forceinline__ void rot_gate(float (&ax)[16], float (&ay)[16], int lane,
                                         float4 gA, float4 gB) {
    if constexpr (P >= 4) {
        const int lb = 1 << (P - 4);
        const bool hi = (lane & lb) != 0;
        const float gdx = hi ? gB.z : gA.x, gdy = hi ? gB.w : gA.y;   // diagonal
        const float gox = hi ? gB.x : gA.z, goy = hi ? gB.y : gA.w;   // off-diagonal
#pragma unroll
        for (int r = 0; r < 16; r++) {
            float ox = lane_xor<lb>(ax[r]);
            float oy = lane_xor<lb>(ay[r]);
            float vx = ax[r], vy = ay[r];
            ax[r] = gdx * vx - gdy * vy + gox * ox - goy * oy;
            ay[r] = gdx * vy + gdy * vx + gox * oy + goy * ox;
        }
    } else {
        const int m = 1 << P;
#pragma unroll
        for (int r = 0; r < 16; r++) {
            if (!(r & m)) {
                const int r1 = r | m;
                float x0 = ax[r], y0 = ay[r], x1 = ax[r1], y1 = ay[r1];
                ax[r]  = gA.x * x0 - gA.y * y0 + gA.z * x1 - gA.w * y1;
                ay[r]  = gA.x * y0 + gA.y * x0 + gA.z * y1 + gA.w * x1;
                ax[r1] = gB.x * x0 - gB.y * y0 + gB.z * x1 - gB.w * y1;
                ay[r1] = gB.x * y0 + gB.y * x0 + gB.z * y1 + gB.w * x1;
            }
        }
    }
}

// ---- rot<9> with the PREVIOUS layer's CNOT(ctrl=reg bit0, tgt=lane bit 32) fused in.
// After that CNOT, odd regs hold their xor-32 partner's value; applying Rot then is the
// same 32 shuffles with (diag, off-diag) coefficient roles swapped for odd regs.
__device__ __forceinline__ void rot9_fused(float (&ax)[16], float (&ay)[16], int lane,
                                           float4 gA, float4 gB) {
    const bool hi = (lane & 32) != 0;
    const float gdx = hi ? gB.z : gA.x, gdy = hi ? gB.w : gA.y;
    const float gox = hi ? gB.x : gA.z, goy = hi ? gB.y : gA.w;
#pragma unroll
    for (int r = 0; r < 16; r++) {
        float ox = __shfl_xor(ax[r], 32, 64);
        float oy = __shfl_xor(ay[r], 32, 64);
        float vx = ax[r], vy = ay[r];
        if (!(r & 1)) {
            ax[r] = gdx * vx - gdy * vy + gox * ox - goy * oy;
            ay[r] = gdx * vy + gdy * vx + gox * oy + goy * ox;
        } else {   // fused CNOT: own/partner roles swapped
            ax[r] = gdx * ox - gdy * oy + gox * vx - goy * vy;
            ay[r] = gdx * oy + gdy * ox + gox * vy + goy * vx;
        }
    }
}

// ---- CNOT: control bit PC, target bit PT (only the non-chain cases remain) ----
template<int PC, int PT>
__device__ __forceinline__ void cnot_gate(float (&ax)[16], float (&ay)[16], int lane) {
    if constexpr (PC >= 4 && PT < 4) {                // lane control, register target
        const int mt = 1 << PT;
        const bool ctl = (lane & (1 << (PC - 4))) != 0;
#pragma unroll
        for (int r = 0; r < 16; r++) {
            if (!(r & mt)) {
                const int r1 = r | mt;
                float x0 = ax[r], y0 = ay[r], x1 = ax[r1], y1 = ay[r1];
                ax[r]  = ctl ? x1 : x0;  ay[r]  = ctl ? y1 : y0;
                ax[r1] = ctl ? x0 : x1;  ay[r1] = ctl ? y0 : y1;
            }
        }
    } else if constexpr (PC < 4 && PT >= 4) {         // register control, lane target
        const int mc = 1 << PC, mt = 1 << (PT - 4);
#pragma unroll
        for (int r = 0; r < 16; r++) {
            if (r & mc) {
                ax[r] = __shfl_xor(ax[r], mt, 64);
                ay[r] = __shfl_xor(ay[r], mt, 64);
            }
        }
    } else {                                          // register-register: free rename
        const int mc = 1 << PC, mt = 1 << PT;
#pragma unroll
        for (int r = 0; r < 16; r++) {
            if ((r & mc) && !(r & mt)) {
                const int r1 = r | mt;
                float t;
                t = ax[r]; ax[r] = ax[r1]; ax[r1] = t;
                t = ay[r]; ay[r] = ay[r1]; ay[r1] = t;
            }
        }
    }
}

__global__ __launch_bounds__(BLOCK)
__attribute__((amdgpu_waves_per_eu(2, 8)))
void qnet_kernel(
    const float* __restrict__ x,
    const float* __restrict__ Wp,
    const float* __restrict__ bp,
    const float* __restrict__ qw,
    const float* __restrict__ Wo,
    const float* __restrict__ bo,
    float* __restrict__ out, int B)
{
    __shared__ __align__(16) float gates[NLAYERS * NQ * 8];  // Rot matrices (batch-independent)

    const int tid   = threadIdx.x;
    const int lane  = tid & 63;
    const int state = blockIdx.x * (BLOCK / 64) + (tid >> 6);

    // ---- Rot gate table (block-shared; the only barrier in the kernel) ----
    if (tid < NLAYERS * NQ) {
        float phi = qw[tid * 3 + 0];
        float th  = qw[tid * 3 + 1];
        float om  = qw[tid * 3 + 2];
        float s, c;   sincosf(0.5f * th, &s, &c);
        float sap, cap; sincosf(0.5f * (phi + om), &sap, &cap);
        float sam, cam; sincosf(0.5f * (phi - om), &sam, &cam);
        float* g = &gates[tid * 8];
        g[0] =  cap * c;  g[1] = -sap * c;   // u00
        g[2] = -cam * s;  g[3] = -sam * s;   // u01
        g[4] =  cam * s;  g[5] = -sam * s;   // u10
        g[6] =  cap * c;  g[7] =  sap * c;   // u11
    }
    __syncthreads();
    if (state >= B) return;

    // ---- projection: h = tanh(x[state] @ Wp^T + bp), one wave per state ----
    float acc[NQ];
#pragma unroll
    for (int q = 0; q < NQ; q++) acc[q] = 0.f;
    const float* xrow = x + (size_t)state * D_IN;
    for (int d = lane; d < D_IN; d += 64) {
        float xv = xrow[d];
#pragma unroll
        for (int q = 0; q < NQ; q++) acc[q] += xv * Wp[q * D_IN + d];
    }
#pragma unroll
    for (int q = 0; q < NQ; q++) {
#pragma unroll
        for (int o = 1; o < 64; o <<= 1) acc[q] += __shfl_xor(acc[q], o, 64);
    }
    // lane q (q<10) owns qubit q's RY coefficients
    float myc = 1.f, mys = 0.f;
    if (lane < NQ) {
        float h = tanhf(acc[lane] + bp[lane]);
        sincosf(0.5f * h, &mys, &myc);
    }

    // ---- statevector |0..0> in registers (SoA) ----
    float ax[16], ay[16];
#pragma unroll
    for (int r = 0; r < 16; r++) { ax[r] = 0.f; ay[r] = 0.f; }
    if (lane == 0) ax[0] = 1.f;

    // Pull-index for the composite lane-CNOT chain: src_lane = Gray(lane)
    const int bidx = (lane ^ (lane >> 1)) << 2;

    // ---- layer 0: RY fused into Rot (U = Rot * RY, wave-uniform) ----
    {
        const float* gl = &gates[0];
        float c, s;
#define FROTQ(Q) \
        c = __shfl(myc, Q, 64); s = __shfl(mys, Q, 64); \
        { float4 gA = *(const float4*)(gl + Q * 8); \
          float4 gB = *(const float4*)(gl + Q * 8 + 4); \
          float4 uA, uB; \
          uA.x = gA.x * c + gA.z * s;  uA.y = gA.y * c + gA.w * s; \
          uA.z = gA.z * c - gA.x * s;  uA.w = gA.w * c - gA.y * s; \
          uB.x = gB.x * c + gB.z * s;  uB.y = gB.y * c + gB.w * s; \
          uB.z = gB.z * c - gB.x * s;  uB.w = gB.w * c - gB.y * s; \
          rot_gate<9 - Q>(ax, ay, lane, uA, uB); }
        FROTQ(0) FROTQ(1) FROTQ(2) FROTQ(3) FROTQ(4)
        FROTQ(5) FROTQ(6) FROTQ(7) FROTQ(8) FROTQ(9)
#undef FROTQ
        // CNOT ring (9,8)..(5,4) as one lane permutation
#pragma unroll
        for (int r = 0; r < 16; r++) {
            ax[r] = __int_as_float(__builtin_amdgcn_ds_bpermute(bidx, __float_as_int(ax[r])));
            ay[r] = __int_as_float(__builtin_amdgcn_ds_bpermute(bidx, __float_as_int(ay[r])));
        }
        cnot_gate<4, 3>(ax, ay, lane);
        cnot_gate<3, 2>(ax, ay, lane);
        cnot_gate<2, 1>(ax, ay, lane);
        cnot_gate<1, 0>(ax, ay, lane);
        // cnot<0,9> fused into next layer's rot<9>
    }

    // ---- layers 1..3 (first gate consumes previous layer's trailing cnot<0,9>) ----
    for (int l = 1; l < NLAYERS; l++) {
        const float* gl = &gates[l * NQ * 8];
        {   float4 gA = *(const float4*)(gl);
            float4 gB = *(const float4*)(gl + 4);
            rot9_fused(ax, ay, lane, gA, gB); }
#define ROTQ(Q) { float4 gA = *(const float4*)(gl + Q * 8); \
                  float4 gB = *(const float4*)(gl + Q * 8 + 4); \
                  rot_gate<9 - Q>(ax, ay, lane, gA, gB); }
        ROTQ(1) ROTQ(2) ROTQ(3) ROTQ(4)
        ROTQ(5) ROTQ(6) ROTQ(7) ROTQ(8) ROTQ(9)
#undef ROTQ
#pragma unroll
        for (int r = 0; r < 16; r++) {
            ax[r] = __int_as_float(__builtin_amdgcn_ds_bpermute(bidx, __float_as_int(ax[r])));
            ay[r] = __int_as_float(__builtin_amdgcn_ds_bpermute(bidx, __float_as_int(ay[r])));
        }
        cnot_gate<4, 3>(ax, ay, lane);
        cnot_gate<3, 2>(ax, ay, lane);
        cnot_gate<2, 1>(ax, ay, lane);
        cnot_gate<1, 0>(ax, ay, lane);
    }
    // layer 3's trailing cnot<0,9> applied for real (measurement follows)
    cnot_gate<0, 9>(ax, ay, lane);

    // ---- measurement: Z expectation per qubit (plain shfl reductions only) ----
    float S = 0.f, zr3 = 0.f, zr2 = 0.f, zr1 = 0.f, zr0 = 0.f;
#pragma unroll
    for (int r = 0; r < 16; r++) {
        float pr = ax[r] * ax[r] + ay[r] * ay[r];
        S += pr;
        zr3 += (r & 8) ? -pr : pr;
        zr2 += (r & 4) ? -pr : pr;
        zr1 += (r & 2) ? -pr : pr;
        zr0 += (r & 1) ? -pr : pr;
    }
    float zq[NQ];
    zq[6] = zr3; zq[7] = zr2; zq[8] = zr1; zq[9] = zr0;       // register qubits
#pragma unroll
    for (int q = 0; q < 6; q++)                                // lane qubits: lane bit 5-q
        zq[q] = ((lane >> (5 - q)) & 1) ? -S : S;
#pragma unroll
    for (int q = 0; q < NQ; q++) {
#pragma unroll
        for (int o = 1; o < 64; o <<= 1) zq[q] += __shfl_xor(zq[q], o, 64);
    }

    // ---- output projection: out[state] = zq @ Wo^T + bo ----
    if (lane < NQ) {
        const float* wrow = Wo + lane * NQ;
        float o = bo[lane];
#pragma unroll
        for (int q = 0; q < NQ; q++) o += zq[q] * wrow[q];
        out[(size_t)state * NQ + lane] = o;
    }
}

extern "C" void kernel_launch(void* const* d_in, const int* in_sizes, int n_in,
                              void* d_out, int out_size, void* d_ws, size_t ws_size,
                              hipStream_t stream) {
    const float* x  = (const float*)d_in[0];
    const float* Wp = (const float*)d_in[1];
    const float* bp = (const float*)d_in[2];
    const float* qw = (const float*)d_in[3];
    const float* Wo = (const float*)d_in[4];
    const float* bo = (const float*)d_in[5];
    float* out = (float*)d_out;

    const int B = in_sizes[0] / D_IN;                    // 8192
    const int blocks = (B + (BLOCK / 64) - 1) / (BLOCK / 64);
    hipLaunchKernelGGL(qnet_kernel, dim3(blocks), dim3(BLOCK), 0, stream,
                       x, Wp, bp, qw, Wo, bo, out, B);
}